// Round 1
// baseline (5262.344 us; speedup 1.0000x reference)
//
#include <hip/hip_runtime.h>

#define NU 150000
#define NI 250000
#define NT 400000            // NU + NI
#define DD 64
#define HOPS 3
#define EN 8000000
#define OUT_STRIDE (4*DD)    // [n][4][64]
#define MESS_SCALE ((float)(1.0/0.9))

// ---------------- hop-0 copy: out[n][0][d] = embed ----------------
__global__ void k_copy0(const float* __restrict__ ue, const float* __restrict__ ie,
                        float* __restrict__ out) {
    int tid = blockIdx.x * blockDim.x + threadIdx.x;   // over NT*DD
    int n = tid >> 6, d = tid & 63;
    float v = (n < NU) ? ue[n * DD + d] : ie[(n - NU) * DD + d];
    out[(size_t)n * OUT_STRIDE + d] = v;
}

// ---------------- pack edge-dropout keep bits (exact floorf semantics) ----------------
__global__ void k_keepbits(const float* __restrict__ edu, unsigned long long* __restrict__ kb) {
    int tid = blockIdx.x * blockDim.x + threadIdx.x;   // over HOPS*EN (multiple of 256)
    float u = edu[tid];
    bool bit = (floorf(0.5f + u) != 0.0f);
    unsigned long long m = __ballot(bit);
    if ((threadIdx.x & 63) == 0) kb[tid >> 6] = m;
}

// ---------------- CSR build ----------------
__global__ void k_hist(const int* __restrict__ rows, int* __restrict__ counts) {
    int e = blockIdx.x * blockDim.x + threadIdx.x;
    if (e < EN) atomicAdd(&counts[rows[e]], 1);
}

#define SCAN_B 1024
__global__ void k_scan1(const int* __restrict__ counts, int* __restrict__ rp,
                        int* __restrict__ bsum) {
    __shared__ int s[SCAN_B];
    int t = threadIdx.x;
    int i = blockIdx.x * SCAN_B + t;
    int c = (i < NT) ? counts[i] : 0;
    s[t] = c;
    __syncthreads();
    for (int off = 1; off < SCAN_B; off <<= 1) {
        int v = s[t];
        int add = (t >= off) ? s[t - off] : 0;
        __syncthreads();
        s[t] = v + add;
        __syncthreads();
    }
    if (i < NT) rp[i] = s[t] - c;                 // block-local exclusive
    if (t == SCAN_B - 1) bsum[blockIdx.x] = s[t]; // block total
}

__global__ void k_scan2(int* __restrict__ bsum, int nb) {
    __shared__ int s[SCAN_B];
    int t = threadIdx.x;
    int c = (t < nb) ? bsum[t] : 0;
    s[t] = c;
    __syncthreads();
    for (int off = 1; off < SCAN_B; off <<= 1) {
        int v = s[t];
        int add = (t >= off) ? s[t - off] : 0;
        __syncthreads();
        s[t] = v + add;
        __syncthreads();
    }
    if (t < nb) bsum[t] = s[t] - c;               // exclusive
}

__global__ void k_scan3(int* __restrict__ rp, const int* __restrict__ bsum) {
    int i = blockIdx.x * SCAN_B + threadIdx.x;
    if (i < NT) rp[i] += bsum[blockIdx.x];
    if (i == 0) rp[NT] = EN;
}

__global__ void k_fill(const int* __restrict__ rows, const int* __restrict__ cols,
                       const float* __restrict__ vals, const int* __restrict__ rp,
                       int* __restrict__ cursor, int* __restrict__ ccol,
                       float* __restrict__ cval, int* __restrict__ ceid) {
    int e = blockIdx.x * blockDim.x + threadIdx.x;
    if (e >= EN) return;
    int r = rows[e];
    int pos = rp[r] + atomicAdd(&cursor[r], 1);
    ccol[pos] = cols[e];
    cval[pos] = vals[e] * 2.0f;    // edge-dropout rescale 1/(1-0.5)
    ceid[pos] = e;
}

// ---------------- one wave per row SpMM + message dropout ----------------
__global__ void __launch_bounds__(256) k_hop(
        const int* __restrict__ rp, const int* __restrict__ ccol,
        const float* __restrict__ cval, const int* __restrict__ ceid,
        const unsigned long long* __restrict__ kb,   // this hop's EN/64 words
        const float* __restrict__ mdu,               // this hop's NT*DD uniforms
        float* __restrict__ out, int hop) {
    int wid = (blockIdx.x * blockDim.x + threadIdx.x) >> 6;   // row id
    int lane = threadIdx.x & 63;
    if (wid >= NT) return;
    int start = rp[wid], end = rp[wid + 1];
    const float* aggbase = out + hop * DD;   // slot `hop` of each row
    float acc = 0.0f;
    for (int e = start; e < end; ++e) {
        int eid = ceid[e];                                   // wave-uniform
        unsigned long long w = kb[eid >> 6];
        if ((w >> (eid & 63)) & 1ull) {                      // uniform branch; skip gather
            int col = ccol[e];
            float v = cval[e];
            acc = fmaf(v, aggbase[(size_t)col * OUT_STRIDE + lane], acc);
        }
    }
    float mu = mdu[(size_t)wid * DD + lane];
    float r = (mu >= 0.1f) ? acc * MESS_SCALE : 0.0f;
    out[(size_t)wid * OUT_STRIDE + (hop + 1) * DD + lane] = r;
}

// ---------------- fallback path (if ws too small): atomic scatter ----------------
__global__ void k_zero123(float* __restrict__ out) {
    int tid = blockIdx.x * blockDim.x + threadIdx.x;  // over NT*3*DD
    int d = tid & 63;
    int q = tid >> 6;
    int n = q / 3, s = q % 3;
    out[(size_t)n * OUT_STRIDE + (s + 1) * DD + d] = 0.0f;
}

__global__ void k_hop_atomic(const int* __restrict__ rows, const int* __restrict__ cols,
                             const float* __restrict__ vals, const float* __restrict__ edu,
                             float* __restrict__ out, int hop) {
    int e = (blockIdx.x * blockDim.x + threadIdx.x) >> 6;
    int lane = threadIdx.x & 63;
    if (e >= EN) return;
    float u = edu[e];
    if (floorf(0.5f + u) == 0.0f) return;
    int r = rows[e], c = cols[e];
    float v = vals[e] * 2.0f;
    float m = v * out[(size_t)c * OUT_STRIDE + hop * DD + lane];
    atomicAdd(&out[(size_t)r * OUT_STRIDE + (hop + 1) * DD + lane], m);
}

__global__ void k_scale(const float* __restrict__ mdu, float* __restrict__ out, int hop) {
    int tid = blockIdx.x * blockDim.x + threadIdx.x;   // over NT*DD
    int n = tid >> 6, d = tid & 63;
    float mu = mdu[(size_t)n * DD + d];
    float* p = &out[(size_t)n * OUT_STRIDE + (hop + 1) * DD + d];
    float a = *p;
    *p = (mu >= 0.1f) ? a * MESS_SCALE : 0.0f;
}

extern "C" void kernel_launch(void* const* d_in, const int* in_sizes, int n_in,
                              void* d_out, int out_size, void* d_ws, size_t ws_size,
                              hipStream_t stream) {
    const float* ue   = (const float*)d_in[0];
    const float* ie   = (const float*)d_in[1];
    const int*   erow = (const int*)d_in[2];
    const int*   ecol = (const int*)d_in[3];
    const float* eval = (const float*)d_in[4];
    const float* edu  = (const float*)d_in[5];   // [3][EN]
    const float* mdu  = (const float*)d_in[6];   // [3][NT][64]
    float* out = (float*)d_out;

    char* ws = (char*)d_ws;
    size_t off = 0;
    auto alloc = [&](size_t bytes) -> char* {
        char* p = ws + off;
        off += (bytes + 511) & ~(size_t)511;
        return p;
    };
    int*   rp     = (int*)alloc((size_t)(NT + 1) * 4);
    int*   counts = (int*)alloc((size_t)NT * 4);
    int*   bsum   = (int*)alloc(4096);
    int*   ccol   = (int*)alloc((size_t)EN * 4);
    float* cval   = (float*)alloc((size_t)EN * 4);
    int*   ceid   = (int*)alloc((size_t)EN * 4);
    unsigned long long* kb = (unsigned long long*)alloc((size_t)HOPS * (EN / 64) * 8);

    const int NBS = (NT + SCAN_B - 1) / SCAN_B;   // 391

    if (off <= ws_size) {
        // -------- CSR path --------
        hipMemsetAsync(counts, 0, (size_t)NT * 4, stream);
        k_copy0<<<NT * DD / 256, 256, 0, stream>>>(ue, ie, out);
        k_keepbits<<<(HOPS * EN) / 256, 256, 0, stream>>>(edu, kb);
        k_hist<<<EN / 256, 256, 0, stream>>>(erow, counts);
        k_scan1<<<NBS, SCAN_B, 0, stream>>>(counts, rp, bsum);
        k_scan2<<<1, SCAN_B, 0, stream>>>(bsum, NBS);
        k_scan3<<<NBS, SCAN_B, 0, stream>>>(rp, bsum);
        hipMemsetAsync(counts, 0, (size_t)NT * 4, stream);
        k_fill<<<EN / 256, 256, 0, stream>>>(erow, ecol, eval, rp, counts, ccol, cval, ceid);
        for (int h = 0; h < HOPS; ++h) {
            k_hop<<<NT / 4, 256, 0, stream>>>(rp, ccol, cval, ceid,
                                              kb + (size_t)h * (EN / 64),
                                              mdu + (size_t)h * NT * DD, out, h);
        }
    } else {
        // -------- atomic fallback --------
        k_copy0<<<NT * DD / 256, 256, 0, stream>>>(ue, ie, out);
        k_zero123<<<NT * 3 * DD / 256, 256, 0, stream>>>(out);
        for (int h = 0; h < HOPS; ++h) {
            k_hop_atomic<<<EN / 4, 256, 0, stream>>>(erow, ecol, eval,
                                                     edu + (size_t)h * EN, out, h);
            k_scale<<<NT * DD / 256, 256, 0, stream>>>(mdu + (size_t)h * NT * DD, out, h);
        }
    }
}